// Round 5
// baseline (405.555 us; speedup 1.0000x reference)
//
#include <hip/hip_runtime.h>

#define NN 100000
#define FB_SH 10                 // fine bucket shift: bucket = col >> 10
#define FB_N  1024               // nodes per bucket
#define NFB   98                 // ceil(100000/1024)
#define BIN_STAGE 128
#define BIN_FLUSH 96

// ================= CSR build v3: fine-bucket binning =================

// ---- bucket histogram ----
__global__ __launch_bounds__(256) void k_hist(const int* __restrict__ coli,
                                              int* __restrict__ chist, int E) {
    __shared__ int h[NFB];
    for (int i = threadIdx.x; i < NFB; i += 256) h[i] = 0;
    __syncthreads();
    int stride = gridDim.x * 256;
    for (int e = blockIdx.x * 256 + threadIdx.x; e < E; e += stride)
        atomicAdd(&h[coli[e] >> FB_SH], 1);
    __syncthreads();
    for (int i = threadIdx.x; i < NFB; i += 256)
        if (h[i]) atomicAdd(&chist[i], h[i]);
}

// ---- scan NFB counts -> cbase/gcursor; off[NN]=E ----
__global__ void k_meta(const int* __restrict__ chist, int* __restrict__ cbase,
                       int* __restrict__ gcursor, int* __restrict__ off, int E) {
    if (threadIdx.x == 0 && blockIdx.x == 0) {
        int s = 0;
        for (int b = 0; b < NFB; ++b) { cbase[b] = s; gcursor[b] = s; s += chist[b]; }
        cbase[NFB] = s;
        off[NN] = E;
    }
}

// ---- binning: scatter packed (row<<10|col_local) into fine-bucket regions ----
__global__ __launch_bounds__(256) void k_bin(
    const int* __restrict__ rowi, const int* __restrict__ coli,
    int* __restrict__ gcursor, unsigned int* __restrict__ cbin, int E)
{
    __shared__ unsigned int stage[NFB][BIN_STAGE];
    __shared__ int lcnt[NFB];
    __shared__ int fbase[NFB];
    __shared__ int fcnt[NFB];
    for (int i = threadIdx.x; i < NFB; i += 256) lcnt[i] = 0;
    __syncthreads();
    int stride = gridDim.x * 256;
    for (int base = blockIdx.x * 256; base < E; base += stride) {
        int e = base + threadIdx.x;
        if (e < E) {
            int col = coli[e];
            int row = rowi[e];
            int b = col >> FB_SH;
            unsigned int val = ((unsigned int)row << FB_SH) | (unsigned int)(col & (FB_N - 1));
            int pos = atomicAdd(&lcnt[b], 1);
            if (pos < BIN_STAGE) stage[b][pos] = val;
            else { int gp = atomicAdd(&gcursor[b], 1); cbin[gp] = val; }  // rare spill
        }
        __syncthreads();
        for (int i = threadIdx.x; i < NFB; i += 256) {
            int c = lcnt[i];
            if (c >= BIN_FLUSH) {
                int fc = min(c, BIN_STAGE);
                fbase[i] = atomicAdd(&gcursor[i], fc);
                fcnt[i] = fc;
            } else fbase[i] = -1;
        }
        __syncthreads();
        for (int b = 0; b < NFB; ++b) {
            int fb = fbase[b];
            if (fb >= 0) {
                int cnt = fcnt[b];
                for (int i = threadIdx.x; i < cnt; i += 256) cbin[fb + i] = stage[b][i];
            }
        }
        __syncthreads();
        for (int i = threadIdx.x; i < NFB; i += 256)
            if (fbase[i] >= 0) lcnt[i] = 0;
        __syncthreads();
    }
    // final flush
    for (int i = threadIdx.x; i < NFB; i += 256) {
        int c = lcnt[i];
        if (c > 0) {
            int fc = min(c, BIN_STAGE);
            fbase[i] = atomicAdd(&gcursor[i], fc);
            fcnt[i] = fc;
        } else fbase[i] = -1;
    }
    __syncthreads();
    for (int b = 0; b < NFB; ++b) {
        int fb = fbase[b];
        if (fb >= 0) {
            int cnt = fcnt[b];
            for (int i = threadIdx.x; i < cnt; i += 256) cbin[fb + i] = stage[b][i];
        }
    }
}

// ---- per-bucket CSR finish: hist -> in-LDS scan -> off/dinv -> place srcs ----
__global__ __launch_bounds__(1024) void k_csr(
    const unsigned int* __restrict__ cbin, const int* __restrict__ cbase,
    int* __restrict__ off, float* __restrict__ dinv,
    int* __restrict__ srcs, int n)
{
    __shared__ int hist[FB_N];
    __shared__ int wsum[16];
    int b = blockIdx.x;
    int beg = cbase[b], end = cbase[b + 1];
    int tid = threadIdx.x;
    hist[tid] = 0;
    __syncthreads();
    // pass A: per-node histogram
    for (int e = beg + tid; e < end; e += 1024)
        atomicAdd(&hist[cbin[e] & (FB_N - 1)], 1);
    __syncthreads();
    // exclusive scan of 1024 counters (1 per thread)
    int v = hist[tid];
    int lane = tid & 63;
    int wid  = tid >> 6;
    int incl = v;
    #pragma unroll
    for (int d = 1; d < 64; d <<= 1) {
        int t = __shfl_up(incl, d, 64);
        if (lane >= d) incl += t;
    }
    if (lane == 63) wsum[wid] = incl;
    __syncthreads();
    if (wid == 0) {
        int ws = (lane < 16) ? wsum[lane] : 0;
        int wincl = ws;
        #pragma unroll
        for (int d = 1; d < 16; d <<= 1) {
            int t = __shfl_up(wincl, d, 64);
            if (lane >= d) wincl += t;
        }
        if (lane < 16) wsum[lane] = wincl - ws;   // exclusive wave base
    }
    __syncthreads();
    int excl = wsum[wid] + incl - v;
    int node = (b << FB_SH) + tid;
    if (node < n) {
        off[node]  = beg + excl;
        dinv[node] = rsqrtf((float)(v + 1));   // +1 self-loop
    }
    __syncthreads();
    hist[tid] = excl;   // becomes cursor
    __syncthreads();
    // pass B: place rows
    for (int e = beg + tid; e < end; e += 1024) {
        unsigned int pv = cbin[e];
        int cl  = (int)(pv & (FB_N - 1));
        int row = (int)(pv >> FB_SH);
        int p = atomicAdd(&hist[cl], 1);
        srcs[beg + p] = row;
    }
}

// ================= GEMM: Y = (X @ W) * dinv[row] =================
template<int DOUT>
__global__ __launch_bounds__(256) void k_gemm_scale(
    const float* __restrict__ X, const float* __restrict__ W,
    const float* __restrict__ dinv, float* __restrict__ Y, int n)
{
    constexpr int TPR = DOUT / 4;
    constexpr int R   = 256 / TPR;
    __shared__ float sW[64 * DOUT];
    __shared__ float sX[R * 64];

    for (int i = threadIdx.x; i < 64 * DOUT; i += 256) sW[i] = W[i];
    int r0 = blockIdx.x * R;
    for (int i = threadIdx.x; i < R * 64; i += 256) {
        int r = r0 + (i >> 6);
        sX[i] = (r < n) ? X[(size_t)r * 64 + (i & 63)] : 0.0f;
    }
    __syncthreads();

    int lr  = threadIdx.x / TPR;
    int c4  = (threadIdx.x % TPR) * 4;
    int row = r0 + lr;
    const float* xr = &sX[lr * 64];
    float4 acc = make_float4(0.f, 0.f, 0.f, 0.f);
    #pragma unroll
    for (int k = 0; k < 64; ++k) {
        float xv = xr[k];
        const float* wr = &sW[k * DOUT + c4];
        acc.x = fmaf(xv, wr[0], acc.x);
        acc.y = fmaf(xv, wr[1], acc.y);
        acc.z = fmaf(xv, wr[2], acc.z);
        acc.w = fmaf(xv, wr[3], acc.w);
    }
    if (row < n) {
        float s = dinv[row];
        acc.x *= s; acc.y *= s; acc.z *= s; acc.w *= s;
        *(float4*)&Y[(size_t)row * DOUT + c4] = acc;
    }
}

// ================= CSR aggregate: O = [relu](dinv[i]*(Y[i] + sum_in Y[src]) + b) ===========
template<bool RELU>
__global__ __launch_bounds__(256) void k_agg64(
    const float* __restrict__ Y, const int* __restrict__ off, const int* __restrict__ srcs,
    const float* __restrict__ dinv, const float* __restrict__ bias,
    float* __restrict__ O, int n)
{
    int node = blockIdx.x * 4 + (threadIdx.x >> 6);
    if (node >= n) return;
    int c = threadIdx.x & 63;
    int j = off[node], end = off[node + 1];
    float s0 = Y[(size_t)node * 64 + c];   // self-loop
    float s1 = 0.f, s2 = 0.f, s3 = 0.f;
    for (; j + 4 <= end; j += 4) {
        int a = srcs[j], b = srcs[j + 1], c2 = srcs[j + 2], d = srcs[j + 3];
        s0 += Y[(size_t)a  * 64 + c];
        s1 += Y[(size_t)b  * 64 + c];
        s2 += Y[(size_t)c2 * 64 + c];
        s3 += Y[(size_t)d  * 64 + c];
    }
    for (; j < end; ++j) s0 += Y[(size_t)srcs[j] * 64 + c];
    float s = (s0 + s1) + (s2 + s3);
    float o = fmaf(dinv[node], s, bias[c]);
    if (RELU) o = fmaxf(o, 0.f);
    O[(size_t)node * 64 + c] = o;
}

template<bool RELU>
__global__ __launch_bounds__(256) void k_agg32(
    const float* __restrict__ Y, const int* __restrict__ off, const int* __restrict__ srcs,
    const float* __restrict__ dinv, const float* __restrict__ bias,
    float* __restrict__ O, int n)
{
    int node = blockIdx.x * 8 + (threadIdx.x >> 5);
    if (node >= n) return;
    int c = threadIdx.x & 31;
    int j = off[node], end = off[node + 1];
    float s0 = Y[(size_t)node * 32 + c];   // self-loop
    float s1 = 0.f, s2 = 0.f, s3 = 0.f;
    for (; j + 4 <= end; j += 4) {
        int a = srcs[j], b = srcs[j + 1], c2 = srcs[j + 2], d = srcs[j + 3];
        s0 += Y[(size_t)a  * 32 + c];
        s1 += Y[(size_t)b  * 32 + c];
        s2 += Y[(size_t)c2 * 32 + c];
        s3 += Y[(size_t)d  * 32 + c];
    }
    for (; j < end; ++j) s0 += Y[(size_t)srcs[j] * 32 + c];
    float s = (s0 + s1) + (s2 + s3);
    float o = fmaf(dinv[node], s, bias[c]);
    if (RELU) o = fmaxf(o, 0.f);
    O[(size_t)node * 32 + c] = o;
}

extern "C" void kernel_launch(void* const* d_in, const int* in_sizes, int n_in,
                              void* d_out, int out_size, void* d_ws, size_t ws_size,
                              hipStream_t stream) {
    const float* x  = (const float*)d_in[0];
    const int*   ei = (const int*)d_in[1];
    const float* W1 = (const float*)d_in[2];
    const float* b1 = (const float*)d_in[3];
    const float* W2 = (const float*)d_in[4];
    const float* b2 = (const float*)d_in[5];
    float* out = (float*)d_out;

    const int n = NN;
    const int E = in_sizes[1] / 2;
    const int* rowi = ei;
    const int* coli = ei + E;

    // workspace layout (cbin aliases Y2: cbin dead after k_csr, Y2 written in layer 2)
    char* p = (char*)d_ws;
    int*   meta   = (int*)p;            p += 512 * 4;   // chist[98],cbase[99],gcursor[98]
    int*   chist  = meta;
    int*   cbase  = meta + 128;
    int*   gcur   = meta + 256;
    int*   off    = (int*)p;            p += (size_t)(n + 1) * 4;
    float* dinv   = (float*)p;          p += (size_t)n * 4;
    int*   srcs   = (int*)p;            p += (size_t)E * 4;
    float* Y1     = (float*)p;          p += (size_t)n * 64 * 4;
    float* H      = (float*)p;          p += (size_t)n * 64 * 4;
    float* Y2     = (float*)p;          p += (size_t)n * 32 * 4;
    unsigned int* cbin = (unsigned int*)Y2;   // alias

    // ---- CSR build (shared across both layers) ----
    hipMemsetAsync(meta, 0, 512 * 4, stream);
    k_hist<<<256, 256, 0, stream>>>(coli, chist, E);
    k_meta<<<1, 64, 0, stream>>>(chist, cbase, gcur, off, E);
    k_bin<<<256, 256, 0, stream>>>(rowi, coli, gcur, cbin, E);
    k_csr<<<NFB, 1024, 0, stream>>>(cbin, cbase, off, dinv, srcs, n);

    // ---- layer 1 (in 64 -> hid 64, relu) ----
    k_gemm_scale<64><<<(n + 15) / 16, 256, 0, stream>>>(x, W1, dinv, Y1, n);
    k_agg64<true><<<(n + 3) / 4, 256, 0, stream>>>(Y1, off, srcs, dinv, b1, H, n);

    // ---- layer 2 (hid 64 -> out 32) ----
    k_gemm_scale<32><<<(n + 31) / 32, 256, 0, stream>>>(H, W2, dinv, Y2, n);
    k_agg32<false><<<(n + 7) / 8, 256, 0, stream>>>(Y2, off, srcs, dinv, b2, out, n);
}

// Round 6
// 237.660 us; speedup vs baseline: 1.7065x; 1.7065x over previous
//
#include <hip/hip_runtime.h>

#define NN 100000
#define FB_SH 10                 // fine bucket shift: bucket = col >> 10
#define FB_N  1024               // nodes per bucket
#define NFB   98                 // ceil(100000/1024)
#define NBLK  256                // binning blocks
#define BH_TOT (NFB * NBLK)      // 25088

// ================= CSR build v4: stable two-pass counting sort =================

// ---- pass 1: per-(block,bucket) histogram ----
__global__ __launch_bounds__(256) void k_hist1(const int* __restrict__ coli,
                                               int* __restrict__ bhist, int E, int chunk) {
    __shared__ int h[NFB];
    for (int i = threadIdx.x; i < NFB; i += 256) h[i] = 0;
    __syncthreads();
    int bk = blockIdx.x;
    int beg = bk * chunk, end = min(E, beg + chunk);
    for (int e = beg + threadIdx.x; e < end; e += 256)
        atomicAdd(&h[coli[e] >> FB_SH], 1);
    __syncthreads();
    for (int i = threadIdx.x; i < NFB; i += 256)
        bhist[i * NBLK + bk] = h[i];   // bucket-major for the scan
}

// ---- scan of bhist[BH_TOT]: local scan + block sums ----
__global__ __launch_bounds__(1024) void k_scanA(int* __restrict__ a,
                                                int* __restrict__ blksum, int n) {
    __shared__ int sh[1024];
    int i = blockIdx.x * 1024 + threadIdx.x;
    int v = (i < n) ? a[i] : 0;
    sh[threadIdx.x] = v;
    __syncthreads();
    #pragma unroll
    for (int d = 1; d < 1024; d <<= 1) {
        int t = (threadIdx.x >= d) ? sh[threadIdx.x - d] : 0;
        __syncthreads();
        sh[threadIdx.x] += t;
        __syncthreads();
    }
    if (i < n) a[i] = sh[threadIdx.x] - v;   // local exclusive
    if (threadIdx.x == 1023) blksum[blockIdx.x] = sh[1023];
}

__global__ void k_scanB(int* __restrict__ blksum, int nb, int* __restrict__ off, int E) {
    if (threadIdx.x == 0 && blockIdx.x == 0) {
        int s = 0;
        for (int b = 0; b < nb; ++b) { int t = blksum[b]; blksum[b] = s; s += t; }
        off[NN] = E;
    }
}

__global__ __launch_bounds__(256) void k_scanC(int* __restrict__ a,
                                               const int* __restrict__ blksum, int n) {
    int i = blockIdx.x * 256 + threadIdx.x;
    if (i < n) a[i] += blksum[i >> 10];
}

// ---- pass 2: place packed (row<<10|col_local) at per-(block,bucket) cursor ----
__global__ __launch_bounds__(256) void k_bin2(
    const int* __restrict__ rowi, const int* __restrict__ coli,
    const int* __restrict__ bbase, unsigned int* __restrict__ cbin, int E, int chunk)
{
    __shared__ int cur[NFB];
    int bk = blockIdx.x;
    for (int i = threadIdx.x; i < NFB; i += 256) cur[i] = bbase[i * NBLK + bk];
    __syncthreads();
    int beg = bk * chunk, end = min(E, beg + chunk);
    for (int e = beg + threadIdx.x; e < end; e += 256) {
        int col = coli[e];
        int row = rowi[e];
        int b = col >> FB_SH;
        unsigned int val = ((unsigned int)row << FB_SH) | (unsigned int)(col & (FB_N - 1));
        int pos = atomicAdd(&cur[b], 1);
        cbin[pos] = val;
    }
}

// ---- per-bucket CSR finish: hist -> in-LDS scan -> off/dinv -> place srcs ----
__global__ __launch_bounds__(1024) void k_csr(
    const unsigned int* __restrict__ cbin, const int* __restrict__ bbase,
    int* __restrict__ off, float* __restrict__ dinv,
    int* __restrict__ srcs, int n, int E)
{
    __shared__ int hist[FB_N];
    __shared__ int wsum[16];
    int b = blockIdx.x;
    int beg = bbase[b * NBLK];
    int end = (b + 1 < NFB) ? bbase[(b + 1) * NBLK] : E;
    int tid = threadIdx.x;
    hist[tid] = 0;
    __syncthreads();
    // pass A: per-node histogram
    for (int e = beg + tid; e < end; e += 1024)
        atomicAdd(&hist[cbin[e] & (FB_N - 1)], 1);
    __syncthreads();
    // exclusive scan of 1024 counters (1 per thread)
    int v = hist[tid];
    int lane = tid & 63;
    int wid  = tid >> 6;
    int incl = v;
    #pragma unroll
    for (int d = 1; d < 64; d <<= 1) {
        int t = __shfl_up(incl, d, 64);
        if (lane >= d) incl += t;
    }
    if (lane == 63) wsum[wid] = incl;
    __syncthreads();
    if (wid == 0) {
        int ws = (lane < 16) ? wsum[lane] : 0;
        int wincl = ws;
        #pragma unroll
        for (int d = 1; d < 16; d <<= 1) {
            int t = __shfl_up(wincl, d, 64);
            if (lane >= d) wincl += t;
        }
        if (lane < 16) wsum[lane] = wincl - ws;   // exclusive wave base
    }
    __syncthreads();
    int excl = wsum[wid] + incl - v;
    int node = (b << FB_SH) + tid;
    if (node < n) {
        off[node]  = beg + excl;
        dinv[node] = rsqrtf((float)(v + 1));   // +1 self-loop
    }
    __syncthreads();
    hist[tid] = excl;   // becomes cursor
    __syncthreads();
    // pass B: place rows
    for (int e = beg + tid; e < end; e += 1024) {
        unsigned int pv = cbin[e];
        int cl  = (int)(pv & (FB_N - 1));
        int row = (int)(pv >> FB_SH);
        int p = atomicAdd(&hist[cl], 1);
        srcs[beg + p] = row;
    }
}

// ================= GEMM: Y = (X @ W) * dinv[row] =================
template<int DOUT>
__global__ __launch_bounds__(256) void k_gemm_scale(
    const float* __restrict__ X, const float* __restrict__ W,
    const float* __restrict__ dinv, float* __restrict__ Y, int n)
{
    constexpr int TPR = DOUT / 4;
    constexpr int R   = 256 / TPR;
    __shared__ float sW[64 * DOUT];
    __shared__ float sX[R * 64];

    for (int i = threadIdx.x; i < 64 * DOUT; i += 256) sW[i] = W[i];
    int r0 = blockIdx.x * R;
    for (int i = threadIdx.x; i < R * 64; i += 256) {
        int r = r0 + (i >> 6);
        sX[i] = (r < n) ? X[(size_t)r * 64 + (i & 63)] : 0.0f;
    }
    __syncthreads();

    int lr  = threadIdx.x / TPR;
    int c4  = (threadIdx.x % TPR) * 4;
    int row = r0 + lr;
    const float* xr = &sX[lr * 64];
    float4 acc = make_float4(0.f, 0.f, 0.f, 0.f);
    #pragma unroll
    for (int k = 0; k < 64; ++k) {
        float xv = xr[k];
        const float* wr = &sW[k * DOUT + c4];
        acc.x = fmaf(xv, wr[0], acc.x);
        acc.y = fmaf(xv, wr[1], acc.y);
        acc.z = fmaf(xv, wr[2], acc.z);
        acc.w = fmaf(xv, wr[3], acc.w);
    }
    if (row < n) {
        float s = dinv[row];
        acc.x *= s; acc.y *= s; acc.z *= s; acc.w *= s;
        *(float4*)&Y[(size_t)row * DOUT + c4] = acc;
    }
}

// ================= CSR aggregate: O = [relu](dinv[i]*(Y[i] + sum_in Y[src]) + b) ===========
template<bool RELU>
__global__ __launch_bounds__(256) void k_agg64(
    const float* __restrict__ Y, const int* __restrict__ off, const int* __restrict__ srcs,
    const float* __restrict__ dinv, const float* __restrict__ bias,
    float* __restrict__ O, int n)
{
    int node = blockIdx.x * 4 + (threadIdx.x >> 6);
    if (node >= n) return;
    int c = threadIdx.x & 63;
    int j = off[node], end = off[node + 1];
    float s0 = Y[(size_t)node * 64 + c];   // self-loop
    float s1 = 0.f, s2 = 0.f, s3 = 0.f;
    for (; j + 4 <= end; j += 4) {
        int a = srcs[j], b = srcs[j + 1], c2 = srcs[j + 2], d = srcs[j + 3];
        s0 += Y[(size_t)a  * 64 + c];
        s1 += Y[(size_t)b  * 64 + c];
        s2 += Y[(size_t)c2 * 64 + c];
        s3 += Y[(size_t)d  * 64 + c];
    }
    for (; j < end; ++j) s0 += Y[(size_t)srcs[j] * 64 + c];
    float s = (s0 + s1) + (s2 + s3);
    float o = fmaf(dinv[node], s, bias[c]);
    if (RELU) o = fmaxf(o, 0.f);
    O[(size_t)node * 64 + c] = o;
}

template<bool RELU>
__global__ __launch_bounds__(256) void k_agg32(
    const float* __restrict__ Y, const int* __restrict__ off, const int* __restrict__ srcs,
    const float* __restrict__ dinv, const float* __restrict__ bias,
    float* __restrict__ O, int n)
{
    int node = blockIdx.x * 8 + (threadIdx.x >> 5);
    if (node >= n) return;
    int c = threadIdx.x & 31;
    int j = off[node], end = off[node + 1];
    float s0 = Y[(size_t)node * 32 + c];   // self-loop
    float s1 = 0.f, s2 = 0.f, s3 = 0.f;
    for (; j + 4 <= end; j += 4) {
        int a = srcs[j], b = srcs[j + 1], c2 = srcs[j + 2], d = srcs[j + 3];
        s0 += Y[(size_t)a  * 32 + c];
        s1 += Y[(size_t)b  * 32 + c];
        s2 += Y[(size_t)c2 * 32 + c];
        s3 += Y[(size_t)d  * 32 + c];
    }
    for (; j < end; ++j) s0 += Y[(size_t)srcs[j] * 32 + c];
    float s = (s0 + s1) + (s2 + s3);
    float o = fmaf(dinv[node], s, bias[c]);
    if (RELU) o = fmaxf(o, 0.f);
    O[(size_t)node * 32 + c] = o;
}

extern "C" void kernel_launch(void* const* d_in, const int* in_sizes, int n_in,
                              void* d_out, int out_size, void* d_ws, size_t ws_size,
                              hipStream_t stream) {
    const float* x  = (const float*)d_in[0];
    const int*   ei = (const int*)d_in[1];
    const float* W1 = (const float*)d_in[2];
    const float* b1 = (const float*)d_in[3];
    const float* W2 = (const float*)d_in[4];
    const float* b2 = (const float*)d_in[5];
    float* out = (float*)d_out;

    const int n = NN;
    const int E = in_sizes[1] / 2;
    const int* rowi = ei;
    const int* coli = ei + E;
    const int chunk = (E + NBLK - 1) / NBLK;

    // workspace layout (cbin aliases Y2: cbin dead after k_csr, Y2 written in layer 2)
    char* p = (char*)d_ws;
    int*   bhist  = (int*)p;            p += (size_t)BH_TOT * 4;   // scanned in place
    int*   blksum = (int*)p;            p += 32 * 4;
    int*   off    = (int*)p;            p += (size_t)(n + 1) * 4;
    float* dinv   = (float*)p;          p += (size_t)n * 4;
    int*   srcs   = (int*)p;            p += (size_t)E * 4;
    float* Y1     = (float*)p;          p += (size_t)n * 64 * 4;
    float* H      = (float*)p;          p += (size_t)n * 64 * 4;
    float* Y2     = (float*)p;          p += (size_t)n * 32 * 4;
    unsigned int* cbin = (unsigned int*)Y2;   // alias

    // ---- CSR build (counting sort, shared across both layers) ----
    k_hist1<<<NBLK, 256, 0, stream>>>(coli, bhist, E, chunk);
    int nbs = (BH_TOT + 1023) / 1024;   // 25
    k_scanA<<<nbs, 1024, 0, stream>>>(bhist, blksum, BH_TOT);
    k_scanB<<<1, 64, 0, stream>>>(blksum, nbs, off, E);
    k_scanC<<<(BH_TOT + 255) / 256, 256, 0, stream>>>(bhist, blksum, BH_TOT);
    k_bin2<<<NBLK, 256, 0, stream>>>(rowi, coli, bhist, cbin, E, chunk);
    k_csr<<<NFB, 1024, 0, stream>>>(cbin, bhist, off, dinv, srcs, n, E);

    // ---- layer 1 (in 64 -> hid 64, relu) ----
    k_gemm_scale<64><<<(n + 15) / 16, 256, 0, stream>>>(x, W1, dinv, Y1, n);
    k_agg64<true><<<(n + 3) / 4, 256, 0, stream>>>(Y1, off, srcs, dinv, b1, H, n);

    // ---- layer 2 (hid 64 -> out 32) ----
    k_gemm_scale<32><<<(n + 31) / 32, 256, 0, stream>>>(H, W2, dinv, Y2, n);
    k_agg32<false><<<(n + 7) / 8, 256, 0, stream>>>(Y2, off, srcs, dinv, b2, out, n);
}

// Round 7
// 204.987 us; speedup vs baseline: 1.9784x; 1.1594x over previous
//
#include <hip/hip_runtime.h>

#define NN 100000
#define FB_SH 10                 // fine bucket shift: bucket = col >> 10
#define FB_N  1024               // nodes per bucket
#define NFB   98                 // ceil(100000/1024)
#define NBLK  256                // binning blocks
#define BH_TOT (NFB * NBLK)      // 25088

// bf16 helpers (RN-even)
static __device__ __forceinline__ unsigned short f2bf(float f) {
    unsigned u = __float_as_uint(f);
    u += 0x7fffu + ((u >> 16) & 1u);
    return (unsigned short)(u >> 16);
}
static __device__ __forceinline__ float bf2f(unsigned short h) {
    return __uint_as_float(((unsigned)h) << 16);
}

// ================= CSR build: stable two-pass counting sort =================

__global__ __launch_bounds__(256) void k_hist1(const int* __restrict__ coli,
                                               int* __restrict__ bhist, int E, int chunk) {
    __shared__ int h[NFB];
    for (int i = threadIdx.x; i < NFB; i += 256) h[i] = 0;
    __syncthreads();
    int bk = blockIdx.x;
    int beg = bk * chunk, end = min(E, beg + chunk);
    for (int e = beg + threadIdx.x; e < end; e += 256)
        atomicAdd(&h[coli[e] >> FB_SH], 1);
    __syncthreads();
    for (int i = threadIdx.x; i < NFB; i += 256)
        bhist[i * NBLK + bk] = h[i];   // bucket-major for the scan
}

__global__ __launch_bounds__(1024) void k_scanA(int* __restrict__ a,
                                                int* __restrict__ blksum, int n) {
    __shared__ int sh[1024];
    int i = blockIdx.x * 1024 + threadIdx.x;
    int v = (i < n) ? a[i] : 0;
    sh[threadIdx.x] = v;
    __syncthreads();
    #pragma unroll
    for (int d = 1; d < 1024; d <<= 1) {
        int t = (threadIdx.x >= d) ? sh[threadIdx.x - d] : 0;
        __syncthreads();
        sh[threadIdx.x] += t;
        __syncthreads();
    }
    if (i < n) a[i] = sh[threadIdx.x] - v;   // local exclusive
    if (threadIdx.x == 1023) blksum[blockIdx.x] = sh[1023];
}

__global__ void k_scanB(int* __restrict__ blksum, int nb, int* __restrict__ off, int E) {
    if (threadIdx.x == 0 && blockIdx.x == 0) {
        int s = 0;
        for (int b = 0; b < nb; ++b) { int t = blksum[b]; blksum[b] = s; s += t; }
        off[NN] = E;
    }
}

__global__ __launch_bounds__(256) void k_scanC(int* __restrict__ a,
                                               const int* __restrict__ blksum, int n) {
    int i = blockIdx.x * 256 + threadIdx.x;
    if (i < n) a[i] += blksum[i >> 10];
}

__global__ __launch_bounds__(256) void k_bin2(
    const int* __restrict__ rowi, const int* __restrict__ coli,
    const int* __restrict__ bbase, unsigned int* __restrict__ cbin, int E, int chunk)
{
    __shared__ int cur[NFB];
    int bk = blockIdx.x;
    for (int i = threadIdx.x; i < NFB; i += 256) cur[i] = bbase[i * NBLK + bk];
    __syncthreads();
    int beg = bk * chunk, end = min(E, beg + chunk);
    for (int e = beg + threadIdx.x; e < end; e += 256) {
        int col = coli[e];
        int row = rowi[e];
        int b = col >> FB_SH;
        unsigned int val = ((unsigned int)row << FB_SH) | (unsigned int)(col & (FB_N - 1));
        int pos = atomicAdd(&cur[b], 1);
        cbin[pos] = val;
    }
}

__global__ __launch_bounds__(1024) void k_csr(
    const unsigned int* __restrict__ cbin, const int* __restrict__ bbase,
    int* __restrict__ off, float* __restrict__ dinv,
    int* __restrict__ srcs, int n, int E)
{
    __shared__ int hist[FB_N];
    __shared__ int wsum[16];
    int b = blockIdx.x;
    int beg = bbase[b * NBLK];
    int end = (b + 1 < NFB) ? bbase[(b + 1) * NBLK] : E;
    int tid = threadIdx.x;
    hist[tid] = 0;
    __syncthreads();
    for (int e = beg + tid; e < end; e += 1024)
        atomicAdd(&hist[cbin[e] & (FB_N - 1)], 1);
    __syncthreads();
    int v = hist[tid];
    int lane = tid & 63;
    int wid  = tid >> 6;
    int incl = v;
    #pragma unroll
    for (int d = 1; d < 64; d <<= 1) {
        int t = __shfl_up(incl, d, 64);
        if (lane >= d) incl += t;
    }
    if (lane == 63) wsum[wid] = incl;
    __syncthreads();
    if (wid == 0) {
        int ws = (lane < 16) ? wsum[lane] : 0;
        int wincl = ws;
        #pragma unroll
        for (int d = 1; d < 16; d <<= 1) {
            int t = __shfl_up(wincl, d, 64);
            if (lane >= d) wincl += t;
        }
        if (lane < 16) wsum[lane] = wincl - ws;
    }
    __syncthreads();
    int excl = wsum[wid] + incl - v;
    int node = (b << FB_SH) + tid;
    if (node < n) {
        off[node]  = beg + excl;
        dinv[node] = rsqrtf((float)(v + 1));   // +1 self-loop
    }
    __syncthreads();
    hist[tid] = excl;   // becomes cursor
    __syncthreads();
    for (int e = beg + tid; e < end; e += 1024) {
        unsigned int pv = cbin[e];
        int cl  = (int)(pv & (FB_N - 1));
        int row = (int)(pv >> FB_SH);
        int p = atomicAdd(&hist[cl], 1);
        srcs[beg + p] = row;
    }
}

// ================= GEMM: Ybf = bf16((X @ W) * dinv[row]) =================
template<int DOUT>
__global__ __launch_bounds__(256) void k_gemm_scale(
    const float* __restrict__ X, const float* __restrict__ W,
    const float* __restrict__ dinv, unsigned short* __restrict__ Ybf, int n)
{
    constexpr int TPR = DOUT / 4;
    constexpr int R   = 256 / TPR;
    __shared__ float sW[64 * DOUT];
    __shared__ float sX[R * 64];

    for (int i = threadIdx.x; i < 64 * DOUT; i += 256) sW[i] = W[i];
    int r0 = blockIdx.x * R;
    for (int i = threadIdx.x; i < R * 64; i += 256) {
        int r = r0 + (i >> 6);
        sX[i] = (r < n) ? X[(size_t)r * 64 + (i & 63)] : 0.0f;
    }
    __syncthreads();

    int lr  = threadIdx.x / TPR;
    int c4  = (threadIdx.x % TPR) * 4;
    int row = r0 + lr;
    const float* xr = &sX[lr * 64];
    float4 acc = make_float4(0.f, 0.f, 0.f, 0.f);
    #pragma unroll
    for (int k = 0; k < 64; ++k) {
        float xv = xr[k];
        const float* wr = &sW[k * DOUT + c4];
        acc.x = fmaf(xv, wr[0], acc.x);
        acc.y = fmaf(xv, wr[1], acc.y);
        acc.z = fmaf(xv, wr[2], acc.z);
        acc.w = fmaf(xv, wr[3], acc.w);
    }
    if (row < n) {
        float s = dinv[row];
        ushort4 o;
        o.x = f2bf(acc.x * s);
        o.y = f2bf(acc.y * s);
        o.z = f2bf(acc.z * s);
        o.w = f2bf(acc.w * s);
        *(ushort4*)&Ybf[(size_t)row * DOUT + c4] = o;
    }
}

// ================= CSR aggregate: O = [relu](dinv[i]*(Y[i] + sum_in Y[src]) + b) ===========
template<bool RELU>
__global__ __launch_bounds__(256) void k_agg64(
    const unsigned short* __restrict__ Ybf, const int* __restrict__ off,
    const int* __restrict__ srcs, const float* __restrict__ dinv,
    const float* __restrict__ bias, float* __restrict__ O, int n)
{
    int node = blockIdx.x * 4 + (threadIdx.x >> 6);
    if (node >= n) return;
    int c = threadIdx.x & 63;
    int j = off[node], end = off[node + 1];
    float s0 = bf2f(Ybf[(size_t)node * 64 + c]);   // self-loop
    float s1 = 0.f, s2 = 0.f, s3 = 0.f, s4 = 0.f, s5 = 0.f, s6 = 0.f, s7 = 0.f;
    for (; j + 8 <= end; j += 8) {
        int i0 = srcs[j],     i1 = srcs[j + 1], i2 = srcs[j + 2], i3 = srcs[j + 3];
        int i4 = srcs[j + 4], i5 = srcs[j + 5], i6 = srcs[j + 6], i7 = srcs[j + 7];
        unsigned short r0 = Ybf[(size_t)i0 * 64 + c];
        unsigned short r1 = Ybf[(size_t)i1 * 64 + c];
        unsigned short r2 = Ybf[(size_t)i2 * 64 + c];
        unsigned short r3 = Ybf[(size_t)i3 * 64 + c];
        unsigned short r4 = Ybf[(size_t)i4 * 64 + c];
        unsigned short r5 = Ybf[(size_t)i5 * 64 + c];
        unsigned short r6 = Ybf[(size_t)i6 * 64 + c];
        unsigned short r7 = Ybf[(size_t)i7 * 64 + c];
        s0 += bf2f(r0); s1 += bf2f(r1); s2 += bf2f(r2); s3 += bf2f(r3);
        s4 += bf2f(r4); s5 += bf2f(r5); s6 += bf2f(r6); s7 += bf2f(r7);
    }
    for (; j < end; ++j) s0 += bf2f(Ybf[(size_t)srcs[j] * 64 + c]);
    float s = ((s0 + s1) + (s2 + s3)) + ((s4 + s5) + (s6 + s7));
    float o = fmaf(dinv[node], s, bias[c]);
    if (RELU) o = fmaxf(o, 0.f);
    O[(size_t)node * 64 + c] = o;
}

template<bool RELU>
__global__ __launch_bounds__(256) void k_agg32(
    const unsigned short* __restrict__ Ybf, const int* __restrict__ off,
    const int* __restrict__ srcs, const float* __restrict__ dinv,
    const float* __restrict__ bias, float* __restrict__ O, int n)
{
    int node = blockIdx.x * 8 + (threadIdx.x >> 5);
    if (node >= n) return;
    int c = threadIdx.x & 31;
    int j = off[node], end = off[node + 1];
    float s0 = bf2f(Ybf[(size_t)node * 32 + c]);   // self-loop
    float s1 = 0.f, s2 = 0.f, s3 = 0.f, s4 = 0.f, s5 = 0.f, s6 = 0.f, s7 = 0.f;
    for (; j + 8 <= end; j += 8) {
        int i0 = srcs[j],     i1 = srcs[j + 1], i2 = srcs[j + 2], i3 = srcs[j + 3];
        int i4 = srcs[j + 4], i5 = srcs[j + 5], i6 = srcs[j + 6], i7 = srcs[j + 7];
        unsigned short r0 = Ybf[(size_t)i0 * 32 + c];
        unsigned short r1 = Ybf[(size_t)i1 * 32 + c];
        unsigned short r2 = Ybf[(size_t)i2 * 32 + c];
        unsigned short r3 = Ybf[(size_t)i3 * 32 + c];
        unsigned short r4 = Ybf[(size_t)i4 * 32 + c];
        unsigned short r5 = Ybf[(size_t)i5 * 32 + c];
        unsigned short r6 = Ybf[(size_t)i6 * 32 + c];
        unsigned short r7 = Ybf[(size_t)i7 * 32 + c];
        s0 += bf2f(r0); s1 += bf2f(r1); s2 += bf2f(r2); s3 += bf2f(r3);
        s4 += bf2f(r4); s5 += bf2f(r5); s6 += bf2f(r6); s7 += bf2f(r7);
    }
    for (; j < end; ++j) s0 += bf2f(Ybf[(size_t)srcs[j] * 32 + c]);
    float s = ((s0 + s1) + (s2 + s3)) + ((s4 + s5) + (s6 + s7));
    float o = fmaf(dinv[node], s, bias[c]);
    if (RELU) o = fmaxf(o, 0.f);
    O[(size_t)node * 32 + c] = o;
}

extern "C" void kernel_launch(void* const* d_in, const int* in_sizes, int n_in,
                              void* d_out, int out_size, void* d_ws, size_t ws_size,
                              hipStream_t stream) {
    const float* x  = (const float*)d_in[0];
    const int*   ei = (const int*)d_in[1];
    const float* W1 = (const float*)d_in[2];
    const float* b1 = (const float*)d_in[3];
    const float* W2 = (const float*)d_in[4];
    const float* b2 = (const float*)d_in[5];
    float* out = (float*)d_out;

    const int n = NN;
    const int E = in_sizes[1] / 2;
    const int* rowi = ei;
    const int* coli = ei + E;
    const int chunk = (E + NBLK - 1) / NBLK;

    // workspace layout, 256 B-aligned segments
    char* p = (char*)d_ws;
    auto alloc = [&p](size_t bytes) { char* q = p; p += (bytes + 255) & ~(size_t)255; return q; };
    int*   bhist  = (int*)alloc((size_t)BH_TOT * 4);
    int*   blksum = (int*)alloc(32 * 4);
    int*   off    = (int*)alloc((size_t)(n + 1) * 4);
    float* dinv   = (float*)alloc((size_t)n * 4);
    int*   srcs   = (int*)alloc((size_t)E * 4);
    unsigned short* Ybf1 = (unsigned short*)alloc((size_t)n * 64 * 2);
    unsigned short* Ybf2 = (unsigned short*)alloc((size_t)n * 32 * 2);
    float* H      = (float*)alloc((size_t)n * 64 * 4);
    unsigned int* cbin = (unsigned int*)H;   // alias: cbin dead before H written

    // ---- CSR build (counting sort, shared across both layers) ----
    k_hist1<<<NBLK, 256, 0, stream>>>(coli, bhist, E, chunk);
    int nbs = (BH_TOT + 1023) / 1024;   // 25
    k_scanA<<<nbs, 1024, 0, stream>>>(bhist, blksum, BH_TOT);
    k_scanB<<<1, 64, 0, stream>>>(blksum, nbs, off, E);
    k_scanC<<<(BH_TOT + 255) / 256, 256, 0, stream>>>(bhist, blksum, BH_TOT);
    k_bin2<<<NBLK, 256, 0, stream>>>(rowi, coli, bhist, cbin, E, chunk);
    k_csr<<<NFB, 1024, 0, stream>>>(cbin, bhist, off, dinv, srcs, n, E);

    // ---- layer 1 (in 64 -> hid 64, relu) ----
    k_gemm_scale<64><<<(n + 15) / 16, 256, 0, stream>>>(x, W1, dinv, Ybf1, n);
    k_agg64<true><<<(n + 3) / 4, 256, 0, stream>>>(Ybf1, off, srcs, dinv, b1, H, n);

    // ---- layer 2 (hid 64 -> out 32) ----
    k_gemm_scale<32><<<(n + 31) / 32, 256, 0, stream>>>(H, W2, dinv, Ybf2, n);
    k_agg32<false><<<(n + 7) / 8, 256, 0, stream>>>(Ybf2, off, srcs, dinv, b2, out, n);
}